// Round 1
// baseline (102.050 us; speedup 1.0000x reference)
//
#include <hip/hip_runtime.h>
#include <math.h>

#define BB 32
#define NN 2048
#define DD 2048
#define KK 5

// Kernel 1: scores[row] = dot(value[row, :], w)   (row = b*N + n)
// One 64-lane wave per row; float4 loads; shuffle reduce.
__global__ __launch_bounds__(256) void score_kernel(const float* __restrict__ value,
                                                    const float* __restrict__ w,
                                                    float* __restrict__ scores) {
    int gwave = (blockIdx.x * blockDim.x + threadIdx.x) >> 6;  // global wave id == row
    int lane  = threadIdx.x & 63;
    if (gwave >= BB * NN) return;

    const float4* vrow = reinterpret_cast<const float4*>(value + (size_t)gwave * DD);
    const float4* w4   = reinterpret_cast<const float4*>(w);

    float acc = 0.0f;
#pragma unroll
    for (int i = 0; i < DD / 256; ++i) {   // 2048 / (64 lanes * 4 floats) = 8 iters
        float4 v  = vrow[i * 64 + lane];
        float4 ww = w4[i * 64 + lane];
        acc += v.x * ww.x + v.y * ww.y + v.z * ww.z + v.w * ww.w;
    }
#pragma unroll
    for (int off = 32; off > 0; off >>= 1)
        acc += __shfl_down(acc, off, 64);

    if (lane == 0) scores[gwave] = acc;
}

// Kernel 2: per-batch top-5 (lowest-index tie-break, descending) + gather rows.
// One block of 256 threads per batch element.
__global__ __launch_bounds__(256) void topk_gather_kernel(const float* __restrict__ scores,
                                                          const float* __restrict__ value,
                                                          float* __restrict__ out) {
    __shared__ float s[NN];
    __shared__ float wbest[4];
    __shared__ int   wbesti[4];
    __shared__ int   sel[KK];

    const int b   = blockIdx.x;
    const int tid = threadIdx.x;
    const int lane = tid & 63;
    const int wv   = tid >> 6;

    for (int i = tid; i < NN; i += 256) s[i] = scores[b * NN + i];
    __syncthreads();

    for (int k = 0; k < KK; ++k) {
        float bv = -INFINITY;
        int   bi = 0x7fffffff;
        for (int i = tid; i < NN; i += 256) {
            float v = s[i];
            if (v > bv) { bv = v; bi = i; }   // within a thread, i is increasing:
                                              // equal later values never replace
        }
#pragma unroll
        for (int off = 32; off > 0; off >>= 1) {
            float ov = __shfl_down(bv, off, 64);
            int   oi = __shfl_down(bi, off, 64);
            if (ov > bv || (ov == bv && oi < bi)) { bv = ov; bi = oi; }
        }
        if (lane == 0) { wbest[wv] = bv; wbesti[wv] = bi; }
        __syncthreads();
        if (tid == 0) {
            float fv = wbest[0]; int fi = wbesti[0];
#pragma unroll
            for (int j = 1; j < 4; ++j) {
                if (wbest[j] > fv || (wbest[j] == fv && wbesti[j] < fi)) {
                    fv = wbest[j]; fi = wbesti[j];
                }
            }
            sel[k] = fi;
            s[fi] = -INFINITY;   // mask winner for next pass
        }
        __syncthreads();
    }

    // Gather the 5 selected rows: out[b, k, :] = value[b, sel[k], :]
    for (int k = 0; k < KK; ++k) {
        const int idx = sel[k];
        const float4* src = reinterpret_cast<const float4*>(value + ((size_t)b * NN + idx) * DD);
        float4*       dst = reinterpret_cast<float4*>(out + ((size_t)b * KK + k) * DD);
        for (int i = tid; i < DD / 4; i += 256) dst[i] = src[i];
    }
}

extern "C" void kernel_launch(void* const* d_in, const int* in_sizes, int n_in,
                              void* d_out, int out_size, void* d_ws, size_t ws_size,
                              hipStream_t stream) {
    const float* value = (const float*)d_in[0];
    const float* w     = (const float*)d_in[1];
    // d_in[2] = b (additive constant, does not affect top-k or gathered values)
    // d_in[3] = num_cxt (fixed at 5)
    float* scores = (float*)d_ws;   // B*N floats = 256 KB
    float* out    = (float*)d_out;

    const int rows   = BB * NN;          // 65536 rows, one wave each
    const int blocks = rows / 4;         // 4 waves (256 threads) per block
    score_kernel<<<blocks, 256, 0, stream>>>(value, w, scores);
    topk_gather_kernel<<<BB, 256, 0, stream>>>(scores, value, out);
}

// Round 3
// 96.107 us; speedup vs baseline: 1.0618x; 1.0618x over previous
//
#include <hip/hip_runtime.h>
#include <math.h>

#define BB 32
#define NN 2048
#define DD 2048
#define KK 5
#define ROWS_PER_WAVE 4

typedef float fx4 __attribute__((ext_vector_type(4)));   // clang vector: OK for nontemporal builtins

// Kernel 1: scores[row] = dot(value[row, :], w)   (row = b*N + n)
// One 64-lane wave per ROWS_PER_WAVE consecutive rows; w cached in registers;
// non-temporal float4 streaming loads for value; shuffle reduce per row.
__global__ __launch_bounds__(256) void score_kernel(const float* __restrict__ value,
                                                    const float* __restrict__ w,
                                                    float* __restrict__ scores) {
    const int lane  = threadIdx.x & 63;
    const int gwave = (blockIdx.x * blockDim.x + threadIdx.x) >> 6;

    // Load w once per wave into registers (8 KB total, L1/L2-resident).
    const fx4* w4 = reinterpret_cast<const fx4*>(w);
    fx4 wr[8];
#pragma unroll
    for (int i = 0; i < 8; ++i) wr[i] = w4[i * 64 + lane];

    const int row0 = gwave * ROWS_PER_WAVE;
#pragma unroll
    for (int r = 0; r < ROWS_PER_WAVE; ++r) {
        const int row = row0 + r;
        const fx4* vrow = reinterpret_cast<const fx4*>(value + (size_t)row * DD);
        float acc = 0.0f;
#pragma unroll
        for (int i = 0; i < 8; ++i) {
            fx4 v = __builtin_nontemporal_load(&vrow[i * 64 + lane]);
            acc += v.x * wr[i].x + v.y * wr[i].y + v.z * wr[i].z + v.w * wr[i].w;
        }
#pragma unroll
        for (int off = 32; off > 0; off >>= 1)
            acc += __shfl_down(acc, off, 64);
        if (lane == 0) scores[row] = acc;
    }
}

// Kernel 2: per-batch top-5 (lowest-index tie-break, descending) + gather rows.
// One block of 256 threads per batch element.
__global__ __launch_bounds__(256) void topk_gather_kernel(const float* __restrict__ scores,
                                                          const float* __restrict__ value,
                                                          float* __restrict__ out) {
    __shared__ float s[NN];
    __shared__ float wbest[4];
    __shared__ int   wbesti[4];
    __shared__ int   sel[KK];

    const int b    = blockIdx.x;
    const int tid  = threadIdx.x;
    const int lane = tid & 63;
    const int wv   = tid >> 6;

    for (int i = tid; i < NN; i += 256) s[i] = scores[b * NN + i];
    __syncthreads();

    for (int k = 0; k < KK; ++k) {
        float bv = -INFINITY;
        int   bi = 0x7fffffff;
        for (int i = tid; i < NN; i += 256) {
            float v = s[i];
            if (v > bv) { bv = v; bi = i; }   // i increasing per thread: ties keep lowest i
        }
#pragma unroll
        for (int off = 32; off > 0; off >>= 1) {
            float ov = __shfl_down(bv, off, 64);
            int   oi = __shfl_down(bi, off, 64);
            if (ov > bv || (ov == bv && oi < bi)) { bv = ov; bi = oi; }
        }
        if (lane == 0) { wbest[wv] = bv; wbesti[wv] = bi; }
        __syncthreads();
        if (tid == 0) {
            float fv = wbest[0]; int fi = wbesti[0];
#pragma unroll
            for (int j = 1; j < 4; ++j) {
                if (wbest[j] > fv || (wbest[j] == fv && wbesti[j] < fi)) {
                    fv = wbest[j]; fi = wbesti[j];
                }
            }
            sel[k] = fi;
            s[fi] = -INFINITY;   // mask winner for next pass
        }
        __syncthreads();
    }

    // Gather the 5 selected rows: out[b, k, :] = value[b, sel[k], :]
    for (int k = 0; k < KK; ++k) {
        const int idx = sel[k];
        const float4* src = reinterpret_cast<const float4*>(value + ((size_t)b * NN + idx) * DD);
        float4*       dst = reinterpret_cast<float4*>(out + ((size_t)b * KK + k) * DD);
        for (int i = tid; i < DD / 4; i += 256) dst[i] = src[i];
    }
}

extern "C" void kernel_launch(void* const* d_in, const int* in_sizes, int n_in,
                              void* d_out, int out_size, void* d_ws, size_t ws_size,
                              hipStream_t stream) {
    const float* value = (const float*)d_in[0];
    const float* w     = (const float*)d_in[1];
    // d_in[2] = b (additive constant, irrelevant to top-k and gathered values)
    // d_in[3] = num_cxt (fixed at 5)
    float* scores = (float*)d_ws;   // B*N floats = 256 KB
    float* out    = (float*)d_out;

    const int waves  = (BB * NN) / ROWS_PER_WAVE;   // 16384 waves
    const int blocks = waves / 4;                   // 4 waves (256 thr) per block
    score_kernel<<<blocks, 256, 0, stream>>>(value, w, scores);
    topk_gather_kernel<<<BB, 256, 0, stream>>>(scores, value, out);
}

// Round 4
// 92.084 us; speedup vs baseline: 1.1082x; 1.0437x over previous
//
#include <hip/hip_runtime.h>
#include <math.h>

#define BB 32
#define NN 2048
#define DD 2048
#define KK 5
#define ROWS_PER_WAVE 4

typedef float fx4 __attribute__((ext_vector_type(4)));   // clang vector: OK for nontemporal builtins

// Kernel 1: scores[row] = dot(value[row, :], w)   (row = b*N + n)
// One wave per 4 consecutive rows. Loads interleaved ACROSS rows (4 independent
// chains) so the VMEM stream has no reduce bubbles; all shuffle reduces at the end.
__global__ __launch_bounds__(256) void score_kernel(const float* __restrict__ value,
                                                    const float* __restrict__ w,
                                                    float* __restrict__ scores) {
    const int lane  = threadIdx.x & 63;
    const int gwave = (blockIdx.x * blockDim.x + threadIdx.x) >> 6;

    // w cached in registers (8 KB, L1-resident load).
    const fx4* w4 = reinterpret_cast<const fx4*>(w);
    fx4 wr[8];
#pragma unroll
    for (int i = 0; i < 8; ++i) wr[i] = w4[i * 64 + lane];

    const int row0 = gwave * ROWS_PER_WAVE;
    const fx4* vrow[ROWS_PER_WAVE];
#pragma unroll
    for (int r = 0; r < ROWS_PER_WAVE; ++r)
        vrow[r] = reinterpret_cast<const fx4*>(value + (size_t)(row0 + r) * DD) + lane;

    float acc[ROWS_PER_WAVE] = {0.f, 0.f, 0.f, 0.f};
#pragma unroll
    for (int i = 0; i < 8; ++i) {          // chunk index within row
#pragma unroll
        for (int r = 0; r < ROWS_PER_WAVE; ++r) {   // 4 independent load chains
            fx4 v = __builtin_nontemporal_load(&vrow[r][i * 64]);
            acc[r] += v.x * wr[i].x + v.y * wr[i].y + v.z * wr[i].z + v.w * wr[i].w;
        }
    }

#pragma unroll
    for (int r = 0; r < ROWS_PER_WAVE; ++r) {
        float a = acc[r];
#pragma unroll
        for (int off = 32; off > 0; off >>= 1)
            a += __shfl_down(a, off, 64);
        if (lane == 0) scores[row0 + r] = a;
    }
}

// Kernel 2: per-batch top-5 (lowest-index tie-break, descending) + gather rows.
// One block of 256 threads per batch element.
__global__ __launch_bounds__(256) void topk_gather_kernel(const float* __restrict__ scores,
                                                          const float* __restrict__ value,
                                                          float* __restrict__ out) {
    __shared__ float s[NN];
    __shared__ float wbest[4];
    __shared__ int   wbesti[4];
    __shared__ int   sel[KK];

    const int b    = blockIdx.x;
    const int tid  = threadIdx.x;
    const int lane = tid & 63;
    const int wv   = tid >> 6;

    for (int i = tid; i < NN; i += 256) s[i] = scores[b * NN + i];
    __syncthreads();

    for (int k = 0; k < KK; ++k) {
        float bv = -INFINITY;
        int   bi = 0x7fffffff;
        for (int i = tid; i < NN; i += 256) {
            float v = s[i];
            if (v > bv) { bv = v; bi = i; }   // i increasing per thread: ties keep lowest i
        }
#pragma unroll
        for (int off = 32; off > 0; off >>= 1) {
            float ov = __shfl_down(bv, off, 64);
            int   oi = __shfl_down(bi, off, 64);
            if (ov > bv || (ov == bv && oi < bi)) { bv = ov; bi = oi; }
        }
        if (lane == 0) { wbest[wv] = bv; wbesti[wv] = bi; }
        __syncthreads();
        if (tid == 0) {
            float fv = wbest[0]; int fi = wbesti[0];
#pragma unroll
            for (int j = 1; j < 4; ++j) {
                if (wbest[j] > fv || (wbest[j] == fv && wbesti[j] < fi)) {
                    fv = wbest[j]; fi = wbesti[j];
                }
            }
            sel[k] = fi;
            s[fi] = -INFINITY;   // mask winner for next pass
        }
        __syncthreads();
    }

    // Gather the 5 selected rows: out[b, k, :] = value[b, sel[k], :]
    for (int k = 0; k < KK; ++k) {
        const int idx = sel[k];
        const float4* src = reinterpret_cast<const float4*>(value + ((size_t)b * NN + idx) * DD);
        float4*       dst = reinterpret_cast<float4*>(out + ((size_t)b * KK + k) * DD);
        for (int i = tid; i < DD / 4; i += 256) dst[i] = src[i];
    }
}

extern "C" void kernel_launch(void* const* d_in, const int* in_sizes, int n_in,
                              void* d_out, int out_size, void* d_ws, size_t ws_size,
                              hipStream_t stream) {
    const float* value = (const float*)d_in[0];
    const float* w     = (const float*)d_in[1];
    // d_in[2] = b (additive constant, irrelevant to top-k and gathered values)
    // d_in[3] = num_cxt (fixed at 5)
    float* scores = (float*)d_ws;   // B*N floats = 256 KB
    float* out    = (float*)d_out;

    const int waves  = (BB * NN) / ROWS_PER_WAVE;   // 16384 waves
    const int blocks = waves / 4;                   // 4 waves (256 thr) per block
    score_kernel<<<blocks, 256, 0, stream>>>(value, w, scores);
    topk_gather_kernel<<<BB, 256, 0, stream>>>(scores, value, out);
}